// Round 1
// baseline (236.630 us; speedup 1.0000x reference)
//
#include <hip/hip_runtime.h>
#include <hip/hip_bf16.h>

typedef __attribute__((ext_vector_type(8))) short short8;
typedef __attribute__((ext_vector_type(4))) float f32x4;

#define DIM 128
#define EPS 1e-6f

__device__ __forceinline__ float wave_sum(float v){
  #pragma unroll
  for (int m = 32; m >= 1; m >>= 1) v += __shfl_xor(v, m);
  return v;
}

// u1[d] = sum_j w1_W[d][j], c1 = sum_j w1_b[j]; same for 2.
__global__ void precompute_kernel(const float* __restrict__ w1_W, const float* __restrict__ w1_b,
                                  const float* __restrict__ w2_W, const float* __restrict__ w2_b,
                                  float* __restrict__ u1, float* __restrict__ u2,
                                  float* __restrict__ c12){
  int d = threadIdx.x;  // 128 threads
  float s1 = 0.f, s2 = 0.f;
  for (int j = 0; j < DIM; ++j){ s1 += w1_W[d*DIM + j]; s2 += w2_W[d*DIM + j]; }
  u1[d] = s1; u2[d] = s2;
  __shared__ float sb1[DIM], sb2[DIM];
  sb1[d] = w1_b[d]; sb2[d] = w2_b[d];
  __syncthreads();
  if (d == 0){
    float c1 = 0.f, c2 = 0.f;
    for (int j = 0; j < DIM; ++j){ c1 += sb1[j]; c2 += sb2[j]; }
    c12[0] = c1; c12[1] = c2;
  }
}

// CSR row_ptr via binary search (adj_row is sorted).
__global__ void row_ptr_kernel(const int* __restrict__ adj_row, int E, int N,
                               int* __restrict__ row_ptr){
  int r = blockIdx.x * blockDim.x + threadIdx.x;
  if (r > N) return;
  int lo = 0, hi = E;
  while (lo < hi){ int mid = (lo + hi) >> 1; if (adj_row[mid] < r) lo = mid + 1; else hi = mid; }
  row_ptr[r] = lo;
}

// LN1 + value = q @ w_W + w_b (bf16 MFMA) + sum1/sum2 = tanh(q.u + c)
__launch_bounds__(256)
__global__ void node_kernel(const float* __restrict__ query,
                            const float* __restrict__ w_W, const float* __restrict__ w_b,
                            const float* __restrict__ ln1_g, const float* __restrict__ ln1_b,
                            const float* __restrict__ u1, const float* __restrict__ u2,
                            const float* __restrict__ c12,
                            float* __restrict__ value, float* __restrict__ sum1,
                            float* __restrict__ sum2, int N){
  __shared__ __hip_bfloat16 A[64][136];    // +8 pad: row stride 272B (16B-aligned, conflict-free)
  __shared__ __hip_bfloat16 WT[128][136];  // W^T: WT[j][d]
  const int tid  = threadIdx.x;
  const int lane = tid & 63;
  const int w    = tid >> 6;
  const int base = blockIdx.x * 64;

  // stage W^T as bf16 (64KB read from L2 per block, cheap)
  for (int idx = tid; idx < DIM*DIM; idx += 256){
    int d = idx >> 7, j = idx & 127;
    WT[j][d] = __float2bfloat16(w_W[idx]);
  }

  float2 u1v = ((const float2*)u1)[lane];
  float2 u2v = ((const float2*)u2)[lane];
  float2 g2  = ((const float2*)ln1_g)[lane];
  float2 b2  = ((const float2*)ln1_b)[lane];
  float c1 = c12[0], c2 = c12[1];

  // LN1: wave w owns nodes [base+16w, base+16w+16); lane holds dims (2l,2l+1)
  for (int i = 0; i < 16; ++i){
    int n = base + w*16 + i;
    float2 qv = make_float2(0.f, 0.f);
    if (n < N) qv = ((const float2*)(query + (size_t)n*DIM))[lane];
    float mean = wave_sum(qv.x + qv.y) * (1.f/128.f);
    float dx = qv.x - mean, dy = qv.y - mean;
    float var = wave_sum(dx*dx + dy*dy) * (1.f/128.f);
    float rs = rsqrtf(var + EPS);
    float nx = g2.x * dx * rs + b2.x;
    float ny = g2.y * dy * rs + b2.y;
    union { __hip_bfloat16 h; unsigned short u; } cx, cy;
    cx.h = __float2bfloat16(nx); cy.h = __float2bfloat16(ny);
    *(unsigned int*)&A[w*16 + i][2*lane] = ((unsigned)cy.u << 16) | (unsigned)cx.u;
    float p1 = wave_sum(nx*u1v.x + ny*u1v.y);
    float p2 = wave_sum(nx*u2v.x + ny*u2v.y);
    if (lane == 0 && n < N){
      sum1[n] = tanhf(p1 + c1);
      sum2[n] = tanhf(p2 + c2);
    }
  }
  __syncthreads();

  // GEMM: wave w computes nodes [16w,16w+16) x all 128 cols via 16x16x32 MFMA
  short8 afr[4];
  #pragma unroll
  for (int ks = 0; ks < 4; ++ks)
    afr[ks] = *(const short8*)&A[w*16 + (lane & 15)][ks*32 + (lane >> 4)*8];

  #pragma unroll
  for (int jb = 0; jb < 8; ++jb){
    f32x4 acc = {0.f, 0.f, 0.f, 0.f};
    #pragma unroll
    for (int ks = 0; ks < 4; ++ks){
      short8 bfr = *(const short8*)&WT[jb*16 + (lane & 15)][ks*32 + (lane >> 4)*8];
      acc = __builtin_amdgcn_mfma_f32_16x16x32_bf16(afr[ks], bfr, acc, 0, 0, 0);
    }
    int col = jb*16 + (lane & 15);            // C/D: col = lane&15, row = (lane>>4)*4 + reg
    float bias = w_b[col];
    int rbase = (lane >> 4) * 4;
    #pragma unroll
    for (int i = 0; i < 4; ++i){
      int n = base + w*16 + rbase + i;
      if (n < N) value[(size_t)n*DIM + col] = acc[i] + bias;
    }
  }
}

// One wave per row: softmax (no max pass needed: logits in (-0.4,2)) + SpMM + fused LN2
__launch_bounds__(256)
__global__ void edge_kernel(const float* __restrict__ adj_val, const int* __restrict__ adj_col,
                            const int* __restrict__ row_ptr,
                            const float* __restrict__ sum1, const float* __restrict__ sum2,
                            const float* __restrict__ value,
                            const float* __restrict__ ln2_g, const float* __restrict__ ln2_b,
                            float* __restrict__ out, int N){
  const int lane = threadIdx.x & 63;
  const int r = blockIdx.x * 4 + (threadIdx.x >> 6);
  if (r >= N) return;
  const int e0 = row_ptr[r], e1 = row_ptr[r+1];
  const float s1 = sum1[r];

  // pass 1: sum of exp(leaky(av*(s1+sum2[col])))
  float s = 0.f;
  for (int cb = e0; cb < e1; cb += 64){
    int e = cb + lane;
    if (e < e1){
      float av = adj_val[e];
      int   c  = adj_col[e];
      float x  = av * (s1 + sum2[c]);
      float lg = x > 0.f ? x : 0.2f * x;
      s += __expf(lg);
    }
  }
  s = wave_sum(s);
  float inv = (s > 0.f) ? 1.f / s : 0.f;

  // pass 2: out[r] = sum_e attn_e * value[col_e]; lane owns dims (2l, 2l+1)
  float2 acc = make_float2(0.f, 0.f);
  for (int cb = e0; cb < e1; cb += 64){
    int e = cb + lane;
    float wgt = 0.f; int c = 0;
    if (e < e1){
      float av = adj_val[e];
      c = adj_col[e];
      float x  = av * (s1 + sum2[c]);
      float lg = x > 0.f ? x : 0.2f * x;
      wgt = __expf(lg) * inv;
    }
    int cnt = min(64, e1 - cb);
    #pragma unroll 4
    for (int k = 0; k < cnt; ++k){
      float wk = __shfl(wgt, k);
      int   ck = __shfl(c,  k);
      float2 v = ((const float2*)(value + (size_t)ck*DIM))[lane];
      acc.x += wk * v.x;
      acc.y += wk * v.y;
    }
  }

  // fused LN2 + store
  float mean = wave_sum(acc.x + acc.y) * (1.f/128.f);
  float dx = acc.x - mean, dy = acc.y - mean;
  float var = wave_sum(dx*dx + dy*dy) * (1.f/128.f);
  float rs = rsqrtf(var + EPS);
  float2 g2 = ((const float2*)ln2_g)[lane];
  float2 b2 = ((const float2*)ln2_b)[lane];
  float2 o;
  o.x = g2.x * dx * rs + b2.x;
  o.y = g2.y * dy * rs + b2.y;
  ((float2*)(out + (size_t)r*DIM))[lane] = o;
}

extern "C" void kernel_launch(void* const* d_in, const int* in_sizes, int n_in,
                              void* d_out, int out_size, void* d_ws, size_t ws_size,
                              hipStream_t stream){
  const float* query   = (const float*)d_in[0];
  const float* adj_val = (const float*)d_in[1];
  const float* w_W     = (const float*)d_in[2];
  const float* w_b     = (const float*)d_in[3];
  const float* w1_W    = (const float*)d_in[4];
  const float* w1_b    = (const float*)d_in[5];
  const float* w2_W    = (const float*)d_in[6];
  const float* w2_b    = (const float*)d_in[7];
  const float* ln1_g   = (const float*)d_in[8];
  const float* ln1_b   = (const float*)d_in[9];
  const float* ln2_g   = (const float*)d_in[10];
  const float* ln2_b   = (const float*)d_in[11];
  const int*   adj_row = (const int*)d_in[12];
  const int*   adj_col = (const int*)d_in[13];

  const int N = in_sizes[0] / DIM;
  const int E = in_sizes[1];

  float* value   = (float*)d_ws;                 // N*128 f32
  float* sum1    = value + (size_t)N * DIM;      // N
  float* sum2    = sum1 + N;                     // N
  int*   row_ptr = (int*)(sum2 + N);             // N+1 (+1 pad)
  float* u1      = (float*)(row_ptr + N + 2);    // 128
  float* u2      = u1 + DIM;                     // 128
  float* c12     = u2 + DIM;                     // 2

  precompute_kernel<<<1, 128, 0, stream>>>(w1_W, w1_b, w2_W, w2_b, u1, u2, c12);
  row_ptr_kernel<<<(N + 1 + 255) / 256, 256, 0, stream>>>(adj_row, E, N, row_ptr);
  node_kernel<<<(N + 63) / 64, 256, 0, stream>>>(query, w_W, w_b, ln1_g, ln1_b,
                                                 u1, u2, c12, value, sum1, sum2, N);
  edge_kernel<<<(N + 3) / 4, 256, 0, stream>>>(adj_val, adj_col, row_ptr, sum1, sum2,
                                               value, ln2_g, ln2_b, (float*)d_out, N);
}

// Round 2
// 149.778 us; speedup vs baseline: 1.5799x; 1.5799x over previous
//
#include <hip/hip_runtime.h>
#include <hip/hip_bf16.h>

typedef __attribute__((ext_vector_type(8))) short short8;
typedef __attribute__((ext_vector_type(8))) unsigned short ushort8;
typedef __attribute__((ext_vector_type(4))) float f32x4;

#define DIM 128
#define EPS 1e-6f

__device__ __forceinline__ float wave_sum(float v){
  #pragma unroll
  for (int m = 32; m >= 1; m >>= 1) v += __shfl_xor(v, m);
  return v;
}

// u1[d] = sum_j w1_W[d][j], c1 = sum_j w1_b[j]; same for 2.
__global__ void precompute_kernel(const float* __restrict__ w1_W, const float* __restrict__ w1_b,
                                  const float* __restrict__ w2_W, const float* __restrict__ w2_b,
                                  float* __restrict__ u1, float* __restrict__ u2,
                                  float* __restrict__ c12){
  int d = threadIdx.x;  // 128 threads
  float s1 = 0.f, s2 = 0.f;
  for (int j = 0; j < DIM; ++j){ s1 += w1_W[d*DIM + j]; s2 += w2_W[d*DIM + j]; }
  u1[d] = s1; u2[d] = s2;
  __shared__ float sb1[DIM], sb2[DIM];
  sb1[d] = w1_b[d]; sb2[d] = w2_b[d];
  __syncthreads();
  if (d == 0){
    float c1 = 0.f, c2 = 0.f;
    for (int j = 0; j < DIM; ++j){ c1 += sb1[j]; c2 += sb2[j]; }
    c12[0] = c1; c12[1] = c2;
  }
}

// wt_bf[j*128 + d] = bf16(w_W[d*128 + j])  (W^T, bf16, 32KB — L1/L2 resident)
__global__ void wt_kernel(const float* __restrict__ w_W, __hip_bfloat16* __restrict__ wt_bf){
  int idx = blockIdx.x * 256 + threadIdx.x;   // 64 blocks x 256 = 16384
  int j = idx >> 7, d = idx & 127;
  wt_bf[idx] = __float2bfloat16(w_W[d*DIM + j]);
}

// CSR row_ptr via binary search (adj_row is sorted).
__global__ void row_ptr_kernel(const int* __restrict__ adj_row, int E, int N,
                               int* __restrict__ row_ptr){
  int r = blockIdx.x * blockDim.x + threadIdx.x;
  if (r > N) return;
  int lo = 0, hi = E;
  while (lo < hi){ int mid = (lo + hi) >> 1; if (adj_row[mid] < r) lo = mid + 1; else hi = mid; }
  row_ptr[r] = lo;
}

// LN1 + value = q @ w_W + w_b (bf16 MFMA, B-fragments direct from global) + sum1/sum2
__launch_bounds__(256)
__global__ void node_kernel(const float* __restrict__ query,
                            const __hip_bfloat16* __restrict__ wt_bf,
                            const float* __restrict__ w_b,
                            const float* __restrict__ ln1_g, const float* __restrict__ ln1_b,
                            const float* __restrict__ u1, const float* __restrict__ u2,
                            const float* __restrict__ c12,
                            __hip_bfloat16* __restrict__ value,
                            float* __restrict__ sum1, float* __restrict__ sum2, int N){
  __shared__ __hip_bfloat16 A[64][136];    // +8 pad; row stride 272B
  const int tid  = threadIdx.x;
  const int lane = tid & 63;
  const int w    = tid >> 6;
  const int base = blockIdx.x * 64;

  float2 u1v = ((const float2*)u1)[lane];
  float2 u2v = ((const float2*)u2)[lane];
  float2 g2  = ((const float2*)ln1_g)[lane];
  float2 b2  = ((const float2*)ln1_b)[lane];
  float c1 = c12[0], c2 = c12[1];

  // LN1: wave w owns nodes [base+16w, base+16w+16); lane holds dims (2l,2l+1)
  for (int i = 0; i < 16; ++i){
    int n = base + w*16 + i;
    float2 qv = make_float2(0.f, 0.f);
    if (n < N) qv = ((const float2*)(query + (size_t)n*DIM))[lane];
    float mean = wave_sum(qv.x + qv.y) * (1.f/128.f);
    float dx = qv.x - mean, dy = qv.y - mean;
    float var = wave_sum(dx*dx + dy*dy) * (1.f/128.f);
    float rs = rsqrtf(var + EPS);
    float nx = g2.x * dx * rs + b2.x;
    float ny = g2.y * dy * rs + b2.y;
    union { __hip_bfloat16 h; unsigned short u; } cx, cy;
    cx.h = __float2bfloat16(nx); cy.h = __float2bfloat16(ny);
    *(unsigned int*)&A[w*16 + i][2*lane] = ((unsigned)cy.u << 16) | (unsigned)cx.u;
    float p1 = wave_sum(nx*u1v.x + ny*u1v.y);
    float p2 = wave_sum(nx*u2v.x + ny*u2v.y);
    if (lane == 0 && n < N){
      sum1[n] = tanhf(p1 + c1);
      sum2[n] = tanhf(p2 + c2);
    }
  }
  __syncthreads();

  // GEMM: wave w computes its 16 nodes x 128 cols via 16x16x32 MFMA
  short8 afr[4];
  #pragma unroll
  for (int ks = 0; ks < 4; ++ks)
    afr[ks] = *(const short8*)&A[w*16 + (lane & 15)][ks*32 + (lane >> 4)*8];

  #pragma unroll
  for (int jb = 0; jb < 8; ++jb){
    f32x4 acc = {0.f, 0.f, 0.f, 0.f};
    #pragma unroll
    for (int ks = 0; ks < 4; ++ks){
      short8 bfr = *(const short8*)(wt_bf + (size_t)(jb*16 + (lane & 15))*DIM + ks*32 + (lane >> 4)*8);
      acc = __builtin_amdgcn_mfma_f32_16x16x32_bf16(afr[ks], bfr, acc, 0, 0, 0);
    }
    int col = jb*16 + (lane & 15);            // C/D: col = lane&15, row = (lane>>4)*4 + reg
    float bias = w_b[col];
    int rbase = (lane >> 4) * 4;
    #pragma unroll
    for (int i = 0; i < 4; ++i){
      int n = base + w*16 + rbase + i;
      if (n < N) value[(size_t)n*DIM + col] = __float2bfloat16(acc[i] + bias);
    }
  }
}

// One wave per row; SINGLE pass: acc += exp(leaky)*value[col] (unnormalized —
// LN2 is scale-invariant so softmax 1/s cancels), quarter-wave = 4 edges/iter.
__launch_bounds__(256)
__global__ void edge_kernel(const float* __restrict__ adj_val, const int* __restrict__ adj_col,
                            const int* __restrict__ row_ptr,
                            const float* __restrict__ sum1, const float* __restrict__ sum2,
                            const __hip_bfloat16* __restrict__ value,
                            const float* __restrict__ ln2_g, const float* __restrict__ ln2_b,
                            float* __restrict__ out, int N){
  const int lane = threadIdx.x & 63;
  const int r = blockIdx.x * 4 + (threadIdx.x >> 6);
  if (r >= N) return;
  const int e0 = row_ptr[r], e1 = row_ptr[r+1];
  const float s1 = sum1[r];
  const int q  = lane >> 4;   // quarter: handles edges k*4+q
  const int lq = lane & 15;   // dims [8*lq, 8*lq+8)
  const unsigned short* vp = (const unsigned short*)value;

  float acc[8];
  #pragma unroll
  for (int j = 0; j < 8; ++j) acc[j] = 0.f;

  for (int cb = e0; cb < e1; cb += 64){
    int e = cb + lane;
    float ex = 0.f; int c = 0;
    if (e < e1){
      float av = adj_val[e];
      c = adj_col[e];
      float x  = av * (s1 + sum2[c]);
      float lg = x > 0.f ? x : 0.2f * x;
      ex = __expf(lg);
    }
    int cnt  = min(64, e1 - cb);
    int kmax = (cnt + 3) >> 2;
    #pragma unroll 4
    for (int k = 0; k < kmax; ++k){
      int src = k*4 + q;
      float wk = __shfl(ex, src);
      int   ck = __shfl(c, src);
      if (src < cnt){
        ushort8 v = *(const ushort8*)(vp + (size_t)ck*DIM + lq*8);
        #pragma unroll
        for (int j = 0; j < 8; ++j)
          acc[j] += wk * __uint_as_float((unsigned)(unsigned short)v[j] << 16);
      }
    }
  }

  // reduce across quarters (all lanes end with full sums, replicated 4x)
  #pragma unroll
  for (int j = 0; j < 8; ++j){
    acc[j] += __shfl_xor(acc[j], 16);
    acc[j] += __shfl_xor(acc[j], 32);
  }

  // fused LN2 (each dim replicated 4x across wave -> /512)
  float loc = 0.f;
  #pragma unroll
  for (int j = 0; j < 8; ++j) loc += acc[j];
  float mean = wave_sum(loc) * (1.f/512.f);
  float d[8]; float vv = 0.f;
  #pragma unroll
  for (int j = 0; j < 8; ++j){ d[j] = acc[j] - mean; vv += d[j]*d[j]; }
  float var = wave_sum(vv) * (1.f/512.f);
  float rs = rsqrtf(var + EPS);

  if (q == 0){
    float4 g0 = ((const float4*)ln2_g)[lq*2], g1 = ((const float4*)ln2_g)[lq*2+1];
    float4 b0 = ((const float4*)ln2_b)[lq*2], b1 = ((const float4*)ln2_b)[lq*2+1];
    float4 o0, o1;
    o0.x = g0.x*d[0]*rs + b0.x; o0.y = g0.y*d[1]*rs + b0.y;
    o0.z = g0.z*d[2]*rs + b0.z; o0.w = g0.w*d[3]*rs + b0.w;
    o1.x = g1.x*d[4]*rs + b1.x; o1.y = g1.y*d[5]*rs + b1.y;
    o1.z = g1.z*d[6]*rs + b1.z; o1.w = g1.w*d[7]*rs + b1.w;
    float4* op = (float4*)(out + (size_t)r*DIM + lq*8);
    op[0] = o0; op[1] = o1;
  }
}

extern "C" void kernel_launch(void* const* d_in, const int* in_sizes, int n_in,
                              void* d_out, int out_size, void* d_ws, size_t ws_size,
                              hipStream_t stream){
  const float* query   = (const float*)d_in[0];
  const float* adj_val = (const float*)d_in[1];
  const float* w_W     = (const float*)d_in[2];
  const float* w_b     = (const float*)d_in[3];
  const float* w1_W    = (const float*)d_in[4];
  const float* w1_b    = (const float*)d_in[5];
  const float* w2_W    = (const float*)d_in[6];
  const float* w2_b    = (const float*)d_in[7];
  const float* ln1_g   = (const float*)d_in[8];
  const float* ln1_b   = (const float*)d_in[9];
  const float* ln2_g   = (const float*)d_in[10];
  const float* ln2_b   = (const float*)d_in[11];
  const int*   adj_row = (const int*)d_in[12];
  const int*   adj_col = (const int*)d_in[13];

  const int N = in_sizes[0] / DIM;
  const int E = in_sizes[1];

  char* ws = (char*)d_ws;
  size_t off = 0;
  __hip_bfloat16* value = (__hip_bfloat16*)(ws + off); off += (size_t)N * DIM * 2;
  float* sum1  = (float*)(ws + off); off += (size_t)N * 4;
  float* sum2  = (float*)(ws + off); off += (size_t)N * 4;
  int* row_ptr = (int*)(ws + off);   off += (size_t)(N + 2) * 4;
  float* u1    = (float*)(ws + off); off += DIM * 4;
  float* u2    = (float*)(ws + off); off += DIM * 4;
  float* c12   = (float*)(ws + off); off += 2 * 4;
  off = (off + 63) & ~(size_t)63;
  __hip_bfloat16* wt_bf = (__hip_bfloat16*)(ws + off);

  precompute_kernel<<<1, 128, 0, stream>>>(w1_W, w1_b, w2_W, w2_b, u1, u2, c12);
  wt_kernel<<<64, 256, 0, stream>>>(w_W, wt_bf);
  row_ptr_kernel<<<(N + 1 + 255) / 256, 256, 0, stream>>>(adj_row, E, N, row_ptr);
  node_kernel<<<(N + 63) / 64, 256, 0, stream>>>(query, wt_bf, w_b, ln1_g, ln1_b,
                                                 u1, u2, c12, value, sum1, sum2, N);
  edge_kernel<<<(N + 3) / 4, 256, 0, stream>>>(adj_val, adj_col, row_ptr, sum1, sum2,
                                               value, ln2_g, ln2_b, (float*)d_out, N);
}

// Round 3
// 131.352 us; speedup vs baseline: 1.8015x; 1.1403x over previous
//
#include <hip/hip_runtime.h>
#include <hip/hip_bf16.h>

typedef __attribute__((ext_vector_type(8))) short short8;
typedef __attribute__((ext_vector_type(8))) unsigned short ushort8;
typedef __attribute__((ext_vector_type(4))) float f32x4;
typedef __attribute__((ext_vector_type(4))) unsigned int uint4v;

#define DIM 128
#define EPS 1e-6f

__device__ __forceinline__ float wave_sum(float v){
  #pragma unroll
  for (int m = 32; m >= 1; m >>= 1) v += __shfl_xor(v, m);
  return v;
}

// u1[d] = sum_j w1_W[d][j], c1 = sum_j w1_b[j]; same for 2.
__global__ void precompute_kernel(const float* __restrict__ w1_W, const float* __restrict__ w1_b,
                                  const float* __restrict__ w2_W, const float* __restrict__ w2_b,
                                  float* __restrict__ u1, float* __restrict__ u2,
                                  float* __restrict__ c12){
  int d = threadIdx.x;  // 128 threads
  float s1 = 0.f, s2 = 0.f;
  for (int j = 0; j < DIM; ++j){ s1 += w1_W[d*DIM + j]; s2 += w2_W[d*DIM + j]; }
  u1[d] = s1; u2[d] = s2;
  __shared__ float sb1[DIM], sb2[DIM];
  sb1[d] = w1_b[d]; sb2[d] = w2_b[d];
  __syncthreads();
  if (d == 0){
    float c1 = 0.f, c2 = 0.f;
    for (int j = 0; j < DIM; ++j){ c1 += sb1[j]; c2 += sb2[j]; }
    c12[0] = c1; c12[1] = c2;
  }
}

// wt_bf[j*128 + d] = bf16(w_W[d*128 + j])  (W^T, bf16, 32KB — L1/L2 resident)
__global__ void wt_kernel(const float* __restrict__ w_W, __hip_bfloat16* __restrict__ wt_bf){
  int idx = blockIdx.x * 256 + threadIdx.x;
  int j = idx >> 7, d = idx & 127;
  wt_bf[idx] = __float2bfloat16(w_W[d*DIM + j]);
}

// CSR row_ptr via binary search (adj_row is sorted).
__global__ void row_ptr_kernel(const int* __restrict__ adj_row, int E, int N,
                               int* __restrict__ row_ptr){
  int r = blockIdx.x * blockDim.x + threadIdx.x;
  if (r > N) return;
  int lo = 0, hi = E;
  while (lo < hi){ int mid = (lo + hi) >> 1; if (adj_row[mid] < r) lo = mid + 1; else hi = mid; }
  row_ptr[r] = lo;
}

// LN1 (16-lane group per node, single-pass var) + value = q@w_W + w_b (bf16 MFMA)
// + sum1/sum2; value stored via LDS repack as coalesced 16B rows.
__launch_bounds__(256)
__global__ void node_kernel(const float* __restrict__ query,
                            const __hip_bfloat16* __restrict__ wt_bf,
                            const float* __restrict__ w_b,
                            const float* __restrict__ ln1_g, const float* __restrict__ ln1_b,
                            const float* __restrict__ u1, const float* __restrict__ u2,
                            const float* __restrict__ c12,
                            __hip_bfloat16* __restrict__ value,
                            float* __restrict__ sum1, float* __restrict__ sum2, int N){
  __shared__ __hip_bfloat16 A[64][136];    // +8 pad; row stride 272B (16B aligned)
  const int tid  = threadIdx.x;
  const int lane = tid & 63;
  const int w    = tid >> 6;
  const int q16  = lane >> 4;    // group 0..3
  const int lq   = lane & 15;    // lane in group; owns dims [8*lq, 8*lq+8)
  const int base = blockIdx.x * 64;

  float uu1[8], uu2[8], gg[8], bv[8];
  {
    const float* p1 = u1 + lq*8; const float* p2 = u2 + lq*8;
    const float* pg = ln1_g + lq*8; const float* pb = ln1_b + lq*8;
    #pragma unroll
    for (int j = 0; j < 8; ++j){ uu1[j]=p1[j]; uu2[j]=p2[j]; gg[j]=pg[j]; bv[j]=pb[j]; }
  }
  const float c1 = c12[0], c2 = c12[1];

  // LN1: group q16 of wave w handles node base + w*16 + it*4 + q16
  #pragma unroll
  for (int it = 0; it < 4; ++it){
    const int row = w*16 + it*4 + q16;
    const int n   = base + row;
    float x[8];
    if (n < N){
      const float* qp = query + (size_t)n*DIM + lq*8;
      #pragma unroll
      for (int j = 0; j < 8; ++j) x[j] = qp[j];
    } else {
      #pragma unroll
      for (int j = 0; j < 8; ++j) x[j] = 0.f;
    }
    float s = 0.f, s2 = 0.f;
    #pragma unroll
    for (int j = 0; j < 8; ++j){ s += x[j]; s2 += x[j]*x[j]; }
    #pragma unroll
    for (int m = 1; m <= 8; m <<= 1){ s += __shfl_xor(s, m); s2 += __shfl_xor(s2, m); }
    const float mean = s * (1.f/128.f);
    const float var  = s2 * (1.f/128.f) - mean*mean;
    const float rs   = rsqrtf(var + EPS);

    float p1 = 0.f, p2 = 0.f;
    unsigned pk[4];
    #pragma unroll
    for (int j = 0; j < 4; ++j){
      float n0 = gg[2*j]   * (x[2*j]   - mean) * rs + bv[2*j];
      float n1 = gg[2*j+1] * (x[2*j+1] - mean) * rs + bv[2*j+1];
      p1 += n0*uu1[2*j] + n1*uu1[2*j+1];
      p2 += n0*uu2[2*j] + n1*uu2[2*j+1];
      union { __hip_bfloat16 h; unsigned short u; } a_, b_;
      a_.h = __float2bfloat16(n0); b_.h = __float2bfloat16(n1);
      pk[j] = ((unsigned)b_.u << 16) | (unsigned)a_.u;
    }
    uint4v pv = { pk[0], pk[1], pk[2], pk[3] };
    *(uint4v*)&A[row][lq*8] = pv;
    #pragma unroll
    for (int m = 1; m <= 8; m <<= 1){ p1 += __shfl_xor(p1, m); p2 += __shfl_xor(p2, m); }
    if (lq == 0 && n < N){
      sum1[n] = tanhf(p1 + c1);
      sum2[n] = tanhf(p2 + c2);
    }
  }
  __syncthreads();

  // GEMM: wave w computes its 16 nodes x 128 cols via 16x16x32 MFMA
  short8 afr[4];
  #pragma unroll
  for (int ks = 0; ks < 4; ++ks)
    afr[ks] = *(const short8*)&A[w*16 + lq][ks*32 + q16*8];

  const int rbase = q16 * 4;
  #pragma unroll
  for (int jb = 0; jb < 8; ++jb){
    f32x4 acc = {0.f, 0.f, 0.f, 0.f};
    #pragma unroll
    for (int ks = 0; ks < 4; ++ks){
      short8 bfr = *(const short8*)(wt_bf + (size_t)(jb*16 + lq)*DIM + ks*32 + q16*8);
      acc = __builtin_amdgcn_mfma_f32_16x16x32_bf16(afr[ks], bfr, acc, 0, 0, 0);
    }
    const int col  = jb*16 + lq;           // C/D: col = lane&15, row = (lane>>4)*4 + reg
    const float bias = w_b[col];
    #pragma unroll
    for (int i = 0; i < 4; ++i)
      A[w*16 + rbase + i][col] = __float2bfloat16(acc[i] + bias);  // own rows only; afr already in regs
  }
  __syncthreads();

  // coalesced bf16 row stores: 256 threads = 64 rows x 4 segs of 32 elems
  const int row = tid >> 2, seg = tid & 3;
  const int n = base + row;
  if (n < N){
    ushort8* dst = (ushort8*)((unsigned short*)value + (size_t)n*DIM + seg*32);
    #pragma unroll
    for (int j = 0; j < 4; ++j)
      dst[j] = *(const ushort8*)&A[row][seg*32 + j*8];
  }
}

// One wave per row; single pass (LN2 is scale-invariant -> softmax 1/s cancels).
// 4 edges per lane per iter = 16 edges/wave-iter, 4 gathers in flight per lane.
// Tail slots need no guard: their shfl source lanes hold ex=0, c=0 -> 0*value[0].
__launch_bounds__(256)
__global__ void edge_kernel(const float* __restrict__ adj_val, const int* __restrict__ adj_col,
                            const int* __restrict__ row_ptr,
                            const float* __restrict__ sum1, const float* __restrict__ sum2,
                            const __hip_bfloat16* __restrict__ value,
                            const float* __restrict__ ln2_g, const float* __restrict__ ln2_b,
                            float* __restrict__ out, int N){
  const int lane = threadIdx.x & 63;
  const int r = blockIdx.x * 4 + (threadIdx.x >> 6);
  if (r >= N) return;
  const int e0 = row_ptr[r], e1 = row_ptr[r+1];
  const float s1 = sum1[r];
  const int q  = lane >> 4;   // quarter
  const int lq = lane & 15;   // dims [8*lq, 8*lq+8)
  const unsigned short* vp = (const unsigned short*)value;

  float acc[8];
  #pragma unroll
  for (int j = 0; j < 8; ++j) acc[j] = 0.f;

  for (int cb = e0; cb < e1; cb += 64){
    int e = cb + lane;
    float ex = 0.f; int c = 0;
    if (e < e1){
      float av = adj_val[e];
      c = adj_col[e];
      float x  = av * (s1 + sum2[c]);
      float lg = x > 0.f ? x : 0.2f * x;
      ex = __expf(lg);
    }
    const int cnt  = min(64, e1 - cb);
    const int kmax = (cnt + 15) >> 4;
    for (int k = 0; k < kmax; ++k){
      const int sbase = k*16 + q*4;
      #pragma unroll
      for (int t = 0; t < 4; ++t){
        float wk = __shfl(ex, sbase + t);
        int   ck = __shfl(c,  sbase + t);
        ushort8 v = *(const ushort8*)(vp + (size_t)ck*DIM + lq*8);
        #pragma unroll
        for (int j = 0; j < 8; ++j)
          acc[j] += wk * __uint_as_float((unsigned)(unsigned short)v[j] << 16);
      }
    }
  }

  // reduce across quarters (dims replicated 4x across wave)
  #pragma unroll
  for (int j = 0; j < 8; ++j){
    acc[j] += __shfl_xor(acc[j], 16);
    acc[j] += __shfl_xor(acc[j], 32);
  }

  // fused LN2 (each dim counted 4x -> /512)
  float loc = 0.f;
  #pragma unroll
  for (int j = 0; j < 8; ++j) loc += acc[j];
  float mean = wave_sum(loc) * (1.f/512.f);
  float d[8]; float vv = 0.f;
  #pragma unroll
  for (int j = 0; j < 8; ++j){ d[j] = acc[j] - mean; vv += d[j]*d[j]; }
  float var = wave_sum(vv) * (1.f/512.f);
  float rs = rsqrtf(var + EPS);

  if (q == 0){
    float4 g0 = ((const float4*)ln2_g)[lq*2], g1 = ((const float4*)ln2_g)[lq*2+1];
    float4 b0 = ((const float4*)ln2_b)[lq*2], b1 = ((const float4*)ln2_b)[lq*2+1];
    float4 o0, o1;
    o0.x = g0.x*d[0]*rs + b0.x; o0.y = g0.y*d[1]*rs + b0.y;
    o0.z = g0.z*d[2]*rs + b0.z; o0.w = g0.w*d[3]*rs + b0.w;
    o1.x = g1.x*d[4]*rs + b1.x; o1.y = g1.y*d[5]*rs + b1.y;
    o1.z = g1.z*d[6]*rs + b1.z; o1.w = g1.w*d[7]*rs + b1.w;
    float4* op = (float4*)(out + (size_t)r*DIM + lq*8);
    op[0] = o0; op[1] = o1;
  }
}

extern "C" void kernel_launch(void* const* d_in, const int* in_sizes, int n_in,
                              void* d_out, int out_size, void* d_ws, size_t ws_size,
                              hipStream_t stream){
  const float* query   = (const float*)d_in[0];
  const float* adj_val = (const float*)d_in[1];
  const float* w_W     = (const float*)d_in[2];
  const float* w_b     = (const float*)d_in[3];
  const float* w1_W    = (const float*)d_in[4];
  const float* w1_b    = (const float*)d_in[5];
  const float* w2_W    = (const float*)d_in[6];
  const float* w2_b    = (const float*)d_in[7];
  const float* ln1_g   = (const float*)d_in[8];
  const float* ln1_b   = (const float*)d_in[9];
  const float* ln2_g   = (const float*)d_in[10];
  const float* ln2_b   = (const float*)d_in[11];
  const int*   adj_row = (const int*)d_in[12];
  const int*   adj_col = (const int*)d_in[13];

  const int N = in_sizes[0] / DIM;
  const int E = in_sizes[1];

  char* ws = (char*)d_ws;
  size_t off = 0;
  __hip_bfloat16* value = (__hip_bfloat16*)(ws + off); off += (size_t)N * DIM * 2;
  float* sum1  = (float*)(ws + off); off += (size_t)N * 4;
  float* sum2  = (float*)(ws + off); off += (size_t)N * 4;
  int* row_ptr = (int*)(ws + off);   off += (size_t)(N + 2) * 4;
  float* u1    = (float*)(ws + off); off += DIM * 4;
  float* u2    = (float*)(ws + off); off += DIM * 4;
  float* c12   = (float*)(ws + off); off += 2 * 4;
  off = (off + 63) & ~(size_t)63;
  __hip_bfloat16* wt_bf = (__hip_bfloat16*)(ws + off);

  precompute_kernel<<<1, 128, 0, stream>>>(w1_W, w1_b, w2_W, w2_b, u1, u2, c12);
  wt_kernel<<<64, 256, 0, stream>>>(w_W, wt_bf);
  row_ptr_kernel<<<(N + 1 + 255) / 256, 256, 0, stream>>>(adj_row, E, N, row_ptr);
  node_kernel<<<(N + 63) / 64, 256, 0, stream>>>(query, wt_bf, w_b, ln1_g, ln1_b,
                                                 u1, u2, c12, value, sum1, sum2, N);
  edge_kernel<<<(N + 3) / 4, 256, 0, stream>>>(adj_val, adj_col, row_ptr, sum1, sum2,
                                               value, ln2_g, ln2_b, (float*)d_out, N);
}

// Round 4
// 125.929 us; speedup vs baseline: 1.8791x; 1.0431x over previous
//
#include <hip/hip_runtime.h>
#include <hip/hip_bf16.h>

typedef __attribute__((ext_vector_type(8))) short short8;
typedef __attribute__((ext_vector_type(8))) unsigned short ushort8;
typedef __attribute__((ext_vector_type(4))) float f32x4;
typedef __attribute__((ext_vector_type(4))) unsigned int uint4v;

#define DIM 128
#define EPS 1e-6f

__device__ __forceinline__ float wave_sum(float v){
  #pragma unroll
  for (int m = 32; m >= 1; m >>= 1) v += __shfl_xor(v, m);
  return v;
}

// u1[d] = sum_j w1_W[d][j], c1 = sum_j w1_b[j]; same for 2.
__global__ void precompute_kernel(const float* __restrict__ w1_W, const float* __restrict__ w1_b,
                                  const float* __restrict__ w2_W, const float* __restrict__ w2_b,
                                  float* __restrict__ u1, float* __restrict__ u2,
                                  float* __restrict__ c12){
  int d = threadIdx.x;  // 128 threads
  float s1 = 0.f, s2 = 0.f;
  for (int j = 0; j < DIM; ++j){ s1 += w1_W[d*DIM + j]; s2 += w2_W[d*DIM + j]; }
  u1[d] = s1; u2[d] = s2;
  __shared__ float sb1[DIM], sb2[DIM];
  sb1[d] = w1_b[d]; sb2[d] = w2_b[d];
  __syncthreads();
  if (d == 0){
    float c1 = 0.f, c2 = 0.f;
    for (int j = 0; j < DIM; ++j){ c1 += sb1[j]; c2 += sb2[j]; }
    c12[0] = c1; c12[1] = c2;
  }
}

// wt_bf[j*128 + d] = bf16(w_W[d*128 + j])  (W^T, bf16, 32KB — L1/L2 resident)
__global__ void wt_kernel(const float* __restrict__ w_W, __hip_bfloat16* __restrict__ wt_bf){
  int idx = blockIdx.x * 256 + threadIdx.x;
  int j = idx >> 7, d = idx & 127;
  wt_bf[idx] = __float2bfloat16(w_W[d*DIM + j]);
}

// CSR row_ptr via binary search (adj_row is sorted).
__global__ void row_ptr_kernel(const int* __restrict__ adj_row, int E, int N,
                               int* __restrict__ row_ptr){
  int r = blockIdx.x * blockDim.x + threadIdx.x;
  if (r > N) return;
  int lo = 0, hi = E;
  while (lo < hi){ int mid = (lo + hi) >> 1; if (adj_row[mid] < r) lo = mid + 1; else hi = mid; }
  row_ptr[r] = lo;
}

// LN1 (16-lane group per node) + value = q@w_W + w_b (bf16 MFMA, M_rep=4) + sum1/sum2
__launch_bounds__(256)
__global__ void node_kernel(const float* __restrict__ query,
                            const __hip_bfloat16* __restrict__ wt_bf,
                            const float* __restrict__ w_b,
                            const float* __restrict__ ln1_g, const float* __restrict__ ln1_b,
                            const float* __restrict__ u1, const float* __restrict__ u2,
                            const float* __restrict__ c12,
                            __hip_bfloat16* __restrict__ value,
                            float* __restrict__ sum1, float* __restrict__ sum2, int N){
  __shared__ __hip_bfloat16 A[64][136];    // +8 pad; row stride 272B (16B aligned)
  const int tid  = threadIdx.x;
  const int lane = tid & 63;
  const int w    = tid >> 6;
  const int q16  = lane >> 4;    // group 0..3
  const int lq   = lane & 15;    // lane in group
  const int base = blockIdx.x * 64;

  float uu1[8], uu2[8], gg[8], bv[8];
  {
    const float* p1 = u1 + lq*8; const float* p2 = u2 + lq*8;
    const float* pg = ln1_g + lq*8; const float* pb = ln1_b + lq*8;
    #pragma unroll
    for (int j = 0; j < 8; ++j){ uu1[j]=p1[j]; uu2[j]=p2[j]; gg[j]=pg[j]; bv[j]=pb[j]; }
  }
  const float c1 = c12[0], c2 = c12[1];

  // LN1: group q16 of wave w handles node base + w*16 + it*4 + q16
  #pragma unroll
  for (int it = 0; it < 4; ++it){
    const int row = w*16 + it*4 + q16;
    const int n   = base + row;
    float x[8];
    if (n < N){
      const float* qp = query + (size_t)n*DIM + lq*8;
      #pragma unroll
      for (int j = 0; j < 8; ++j) x[j] = qp[j];
    } else {
      #pragma unroll
      for (int j = 0; j < 8; ++j) x[j] = 0.f;
    }
    float s = 0.f, s2 = 0.f;
    #pragma unroll
    for (int j = 0; j < 8; ++j){ s += x[j]; s2 += x[j]*x[j]; }
    #pragma unroll
    for (int m = 1; m <= 8; m <<= 1){ s += __shfl_xor(s, m); s2 += __shfl_xor(s2, m); }
    const float mean = s * (1.f/128.f);
    const float var  = s2 * (1.f/128.f) - mean*mean;
    const float rs   = rsqrtf(var + EPS);

    float p1 = 0.f, p2 = 0.f;
    unsigned pk[4];
    #pragma unroll
    for (int j = 0; j < 4; ++j){
      float n0 = gg[2*j]   * (x[2*j]   - mean) * rs + bv[2*j];
      float n1 = gg[2*j+1] * (x[2*j+1] - mean) * rs + bv[2*j+1];
      p1 += n0*uu1[2*j] + n1*uu1[2*j+1];
      p2 += n0*uu2[2*j] + n1*uu2[2*j+1];
      union { __hip_bfloat16 h; unsigned short u; } a_, b_;
      a_.h = __float2bfloat16(n0); b_.h = __float2bfloat16(n1);
      pk[j] = ((unsigned)b_.u << 16) | (unsigned)a_.u;
    }
    uint4v pv = { pk[0], pk[1], pk[2], pk[3] };
    *(uint4v*)&A[row][lq*8] = pv;
    #pragma unroll
    for (int m = 1; m <= 8; m <<= 1){ p1 += __shfl_xor(p1, m); p2 += __shfl_xor(p2, m); }
    if (lq == 0 && n < N){
      sum1[n] = tanhf(p1 + c1);
      sum2[n] = tanhf(p2 + c2);
    }
  }
  __syncthreads();

  // GEMM: each wave computes ALL 64 rows x its 32-col slice (4 MFMA per B-load)
  short8 afr[4][4];
  #pragma unroll
  for (int m = 0; m < 4; ++m)
    #pragma unroll
    for (int ks = 0; ks < 4; ++ks)
      afr[m][ks] = *(const short8*)&A[m*16 + lq][ks*32 + q16*8];
  __syncthreads();   // all waves done reading A before C overwrites it

  #pragma unroll
  for (int jj = 0; jj < 2; ++jj){
    const int jb = w*2 + jj;
    f32x4 acc[4];
    #pragma unroll
    for (int m = 0; m < 4; ++m) acc[m] = (f32x4){0.f,0.f,0.f,0.f};
    #pragma unroll
    for (int ks = 0; ks < 4; ++ks){
      short8 bfr = *(const short8*)(wt_bf + (size_t)(jb*16 + lq)*DIM + ks*32 + q16*8);
      #pragma unroll
      for (int m = 0; m < 4; ++m)
        acc[m] = __builtin_amdgcn_mfma_f32_16x16x32_bf16(afr[m][ks], bfr, acc[m], 0, 0, 0);
    }
    const int col  = jb*16 + lq;           // C/D: col = lane&15, row = (lane>>4)*4 + reg
    const float bias = w_b[col];
    #pragma unroll
    for (int m = 0; m < 4; ++m)
      #pragma unroll
      for (int i = 0; i < 4; ++i)
        A[m*16 + q16*4 + i][col] = __float2bfloat16(acc[m][i] + bias);
  }
  __syncthreads();

  // coalesced bf16 row stores: 256 threads = 64 rows x 4 segs of 32 elems
  const int row = tid >> 2, seg = tid & 3;
  const int n = base + row;
  if (n < N){
    ushort8* dst = (ushort8*)((unsigned short*)value + (size_t)n*DIM + seg*32);
    #pragma unroll
    for (int j = 0; j < 4; ++j)
      dst[j] = *(const ushort8*)&A[row][seg*32 + j*8];
  }
}

// Per-edge weight precompute: excol[e] = {exp(leaky(av*(s1[row]+s2[col]))), col}
__global__ void pack_kernel(const float* __restrict__ adj_val, const int* __restrict__ adj_row,
                            const int* __restrict__ adj_col,
                            const float* __restrict__ sum1, const float* __restrict__ sum2,
                            float2* __restrict__ excol, int E){
  int e = blockIdx.x * 256 + threadIdx.x;
  if (e >= E) return;
  float av = adj_val[e];
  int r = adj_row[e], c = adj_col[e];
  float x = av * (sum1[r] + sum2[c]);
  float lg = x > 0.f ? x : 0.2f * x;
  excol[e] = make_float2(__expf(lg), __int_as_float(c));
}

// One wave per row; single pass (LN2 scale-invariance cancels softmax 1/s).
// Quarter q handles edges e0+q, e0+q+4, ...: broadcast 8B excol read (no shuffles),
// 4 independent 16B value gathers in flight. Tail slots: wk=0, c=0 -> +0.
__launch_bounds__(256)
__global__ void edge_kernel(const float2* __restrict__ excol, const int* __restrict__ row_ptr,
                            const __hip_bfloat16* __restrict__ value,
                            const float* __restrict__ ln2_g, const float* __restrict__ ln2_b,
                            float* __restrict__ out, int N){
  const int lane = threadIdx.x & 63;
  const int r = blockIdx.x * 4 + (threadIdx.x >> 6);
  if (r >= N) return;
  const int e0 = row_ptr[r], e1 = row_ptr[r+1];
  const int q  = lane >> 4;   // quarter
  const int lq = lane & 15;   // owns dims [8*lq, 8*lq+8)
  const unsigned int* vp32 = (const unsigned int*)value;

  float acc[8];
  #pragma unroll
  for (int j = 0; j < 8; ++j) acc[j] = 0.f;

  for (int eb = e0 + q; eb < e1; eb += 16){
    #pragma unroll
    for (int t = 0; t < 4; ++t){
      const int e = eb + t*4;
      float2 ecv = (e < e1) ? excol[e] : make_float2(0.f, __int_as_float(0));
      const float wk = ecv.x;
      const int   ck = __float_as_int(ecv.y);
      uint4v v = *(const uint4v*)(vp32 + ((size_t)ck << 6) + lq*4);
      #pragma unroll
      for (int jw = 0; jw < 4; ++jw){
        float lo = __uint_as_float(v[jw] << 16);
        float hi = __uint_as_float(v[jw] & 0xffff0000u);
        acc[2*jw]   += wk * lo;
        acc[2*jw+1] += wk * hi;
      }
    }
  }

  // reduce across quarters (dims replicated 4x across wave)
  #pragma unroll
  for (int j = 0; j < 8; ++j){
    acc[j] += __shfl_xor(acc[j], 16);
    acc[j] += __shfl_xor(acc[j], 32);
  }

  // fused LN2 (each dim counted 4x -> /512)
  float loc = 0.f;
  #pragma unroll
  for (int j = 0; j < 8; ++j) loc += acc[j];
  float mean = wave_sum(loc) * (1.f/512.f);
  float d[8]; float vv = 0.f;
  #pragma unroll
  for (int j = 0; j < 8; ++j){ d[j] = acc[j] - mean; vv += d[j]*d[j]; }
  float var = wave_sum(vv) * (1.f/512.f);
  float rs = rsqrtf(var + EPS);

  if (q == 0){
    float4 g0 = ((const float4*)ln2_g)[lq*2], g1 = ((const float4*)ln2_g)[lq*2+1];
    float4 b0 = ((const float4*)ln2_b)[lq*2], b1 = ((const float4*)ln2_b)[lq*2+1];
    float4 o0, o1;
    o0.x = g0.x*d[0]*rs + b0.x; o0.y = g0.y*d[1]*rs + b0.y;
    o0.z = g0.z*d[2]*rs + b0.z; o0.w = g0.w*d[3]*rs + b0.w;
    o1.x = g1.x*d[4]*rs + b1.x; o1.y = g1.y*d[5]*rs + b1.y;
    o1.z = g1.z*d[6]*rs + b1.z; o1.w = g1.w*d[7]*rs + b1.w;
    float4* op = (float4*)(out + (size_t)r*DIM + lq*8);
    op[0] = o0; op[1] = o1;
  }
}

extern "C" void kernel_launch(void* const* d_in, const int* in_sizes, int n_in,
                              void* d_out, int out_size, void* d_ws, size_t ws_size,
                              hipStream_t stream){
  const float* query   = (const float*)d_in[0];
  const float* adj_val = (const float*)d_in[1];
  const float* w_W     = (const float*)d_in[2];
  const float* w_b     = (const float*)d_in[3];
  const float* w1_W    = (const float*)d_in[4];
  const float* w1_b    = (const float*)d_in[5];
  const float* w2_W    = (const float*)d_in[6];
  const float* w2_b    = (const float*)d_in[7];
  const float* ln1_g   = (const float*)d_in[8];
  const float* ln1_b   = (const float*)d_in[9];
  const float* ln2_g   = (const float*)d_in[10];
  const float* ln2_b   = (const float*)d_in[11];
  const int*   adj_row = (const int*)d_in[12];
  const int*   adj_col = (const int*)d_in[13];

  const int N = in_sizes[0] / DIM;
  const int E = in_sizes[1];

  char* ws = (char*)d_ws;
  size_t off = 0;
  __hip_bfloat16* value = (__hip_bfloat16*)(ws + off); off += (size_t)N * DIM * 2;
  float* sum1   = (float*)(ws + off); off += (size_t)N * 4;
  float* sum2   = (float*)(ws + off); off += (size_t)N * 4;
  int* row_ptr  = (int*)(ws + off);   off += (size_t)(N + 2) * 4;
  float* u1     = (float*)(ws + off); off += DIM * 4;
  float* u2     = (float*)(ws + off); off += DIM * 4;
  float* c12    = (float*)(ws + off); off += 2 * 4;
  off = (off + 63) & ~(size_t)63;
  __hip_bfloat16* wt_bf = (__hip_bfloat16*)(ws + off); off += DIM * DIM * 2;
  off = (off + 63) & ~(size_t)63;
  float2* excol = (float2*)(ws + off);

  precompute_kernel<<<1, 128, 0, stream>>>(w1_W, w1_b, w2_W, w2_b, u1, u2, c12);
  wt_kernel<<<64, 256, 0, stream>>>(w_W, wt_bf);
  row_ptr_kernel<<<(N + 1 + 255) / 256, 256, 0, stream>>>(adj_row, E, N, row_ptr);
  node_kernel<<<(N + 63) / 64, 256, 0, stream>>>(query, wt_bf, w_b, ln1_g, ln1_b,
                                                 u1, u2, c12, value, sum1, sum2, N);
  pack_kernel<<<(E + 255) / 256, 256, 0, stream>>>(adj_val, adj_row, adj_col,
                                                   sum1, sum2, excol, E);
  edge_kernel<<<(N + 3) / 4, 256, 0, stream>>>(excol, row_ptr, value,
                                               ln2_g, ln2_b, (float*)d_out, N);
}